// Round 8
// baseline (33.201 us; speedup 1.0000x reference)
//
#include <hip/hip_runtime.h>

#define N_ATOMS  1536
#define FEAT     32
#define N_GAUSS  16
#define MAXNBR   128   // ~30 expected neighbors; 128 = +18 sigma

// Single-node design: one wave (64 threads) per atom, R6 body; tail reduction
// done by block 0 via per-block DONE flags (distinct addresses -> parallel,
// no same-address RMW serialization, which cost ~13ns each in R2/R7).
// Flags live in d_ws: poison 0xAA != 1 reads as "not done" (replay 1 safe);
// block 0 resets them to 0 before exiting (replays 2+ safe).
__global__ __launch_bounds__(64) void gnn_fused_kernel(
    const float* __restrict__ xyz, const int* __restrict__ z,
    const float* __restrict__ emb, const float* __restrict__ W1,
    const float* __restrict__ b1,  const float* __restrict__ W2,
    const float* __restrict__ b2,  const float* __restrict__ W3,
    const float* __restrict__ b3,
    float* __restrict__ e_atom, int* __restrict__ flags,
    float* __restrict__ out)
{
    const int i   = blockIdx.x;
    const int tid = threadIdx.x;

    __shared__ int   s_nbr[MAXNBR];
    __shared__ float s_dist[MAXNBR];
    __shared__ float s_x[FEAT];
    __shared__ int   s_cnt;

    if (tid == 0) s_cnt = 0;
    __syncthreads();

    const float xi = xyz[3*i+0], yi = xyz[3*i+1], zi = xyz[3*i+2];

    // ---- Phase A: scan all atoms (24 iters), compact hits into LDS queue ----
    for (int j = tid; j < N_ATOMS; j += 64) {
        float dx = xyz[3*j+0] - xi;
        float dy = xyz[3*j+1] - yi;
        float dz = xyz[3*j+2] - zi;
        dx += (dx < -15.0f ? 30.0f : 0.0f) - (dx >= 15.0f ? 30.0f : 0.0f);
        dy += (dy < -15.0f ? 30.0f : 0.0f) - (dy >= 15.0f ? 30.0f : 0.0f);
        dz += (dz < -15.0f ? 30.0f : 0.0f) - (dz >= 15.0f ? 30.0f : 0.0f);
        float d2 = dx*dx + dy*dy + dz*dz;
        if (d2 < 25.0f && d2 > 0.0f) {
            int slot = atomicAdd(&s_cnt, 1);
            if (slot < MAXNBR) { s_nbr[slot] = j; s_dist[slot] = sqrtf(d2); }
        }
    }
    __syncthreads();
    const int cnt = min(s_cnt, MAXNBR);

    // ---- Phase B: 8 lanes per pair, 4 features per lane; g-outer (no rbf[]) ----
    const int fl   = tid & 7;
    const int slot = tid >> 3;
    const float4 b1v = *(const float4*)&b1[fl*4];
    float af[4] = {0.0f, 0.0f, 0.0f, 0.0f};

    for (int p = slot; p < cnt; p += 8) {
        const int   j  = s_nbr[p];
        const float d  = s_dist[p];
        const int   zj = z[j];
        float s0 = b1v.x, s1 = b1v.y, s2 = b1v.z, s3 = b1v.w;
        #pragma unroll
        for (int g = 0; g < N_GAUSS; ++g) {
            float t = d - (float)g * (5.0f / 15.0f);
            float r = __expf(-10.0f * t * t);
            const float4 w = *(const float4*)&W1[g * FEAT + fl * 4];
            s0 = fmaf(r, w.x, s0); s1 = fmaf(r, w.y, s1);
            s2 = fmaf(r, w.z, s2); s3 = fmaf(r, w.w, s3);
        }
        const float4 hj = *(const float4*)&emb[zj * FEAT + fl * 4];
        float sv[4] = {s0, s1, s2, s3};
        float hv[4] = {hj.x, hj.y, hj.z, hj.w};
        #pragma unroll
        for (int ff = 0; ff < 4; ++ff) {
            float t2 = __expf(-2.0f * fabsf(sv[ff]));
            float th = copysignf((1.0f - t2) / (1.0f + t2), sv[ff]);
            af[ff] = fmaf(th, hv[ff], af[ff]);
        }
    }

    #pragma unroll
    for (int ff = 0; ff < 4; ++ff) {
        af[ff] += __shfl_xor(af[ff], 8,  64);
        af[ff] += __shfl_xor(af[ff], 16, 64);
        af[ff] += __shfl_xor(af[ff], 32, 64);
    }

    if (tid < 8) {
        const float4 hi = *(const float4*)&emb[z[i] * FEAT + tid * 4];
        s_x[tid*4+0] = af[0] + hi.x;
        s_x[tid*4+1] = af[1] + hi.y;
        s_x[tid*4+2] = af[2] + hi.z;
        s_x[tid*4+3] = af[3] + hi.w;
    }
    __syncthreads();

    // ---- fused per-atom MLP on lanes 0..31 ----
    float e = 0.0f;
    if (tid < FEAT) {
        float s = b2[tid];
        #pragma unroll
        for (int k = 0; k < FEAT; ++k)
            s = fmaf(s_x[k], W2[k * FEAT + tid], s);
        float u = s / (1.0f + __expf(-s));   // silu
        e = u * W3[tid];
    }
    e += __shfl_xor(e, 16, 64);
    e += __shfl_xor(e, 8,  64);
    e += __shfl_xor(e, 4,  64);
    e += __shfl_xor(e, 2,  64);
    e += __shfl_xor(e, 1,  64);

    if (tid == 0) {
        __hip_atomic_store(&e_atom[i], e, __ATOMIC_RELAXED, __HIP_MEMORY_SCOPE_AGENT);
        __hip_atomic_store(&flags[i], 1, __ATOMIC_RELEASE, __HIP_MEMORY_SCOPE_AGENT);
    }

    // ---- block 0: wait for all flags (distinct addresses, no RMW), reduce ----
    if (i == 0) {
        for (;;) {
            bool mine = true;
            #pragma unroll
            for (int k = 0; k < N_ATOMS / 64; ++k)
                mine &= (__hip_atomic_load(&flags[tid + k * 64],
                         __ATOMIC_ACQUIRE, __HIP_MEMORY_SCOPE_AGENT) == 1);
            if (__all(mine)) break;
            __builtin_amdgcn_s_sleep(2);
        }
        float s = 0.0f;
        #pragma unroll
        for (int k = 0; k < N_ATOMS / 64; ++k)
            s += __hip_atomic_load(&e_atom[tid + k * 64],
                                   __ATOMIC_RELAXED, __HIP_MEMORY_SCOPE_AGENT);
        #pragma unroll
        for (int off = 32; off > 0; off >>= 1)
            s += __shfl_xor(s, off, 64);
        if (tid == 0) out[0] = s + (float)N_ATOMS * b3[0];
        // reset flags for the next graph replay (kernel-exit release publishes)
        #pragma unroll
        for (int k = 0; k < N_ATOMS / 64; ++k)
            __hip_atomic_store(&flags[tid + k * 64], 0,
                               __ATOMIC_RELAXED, __HIP_MEMORY_SCOPE_AGENT);
    }
}

extern "C" void kernel_launch(void* const* d_in, const int* in_sizes, int n_in,
                              void* d_out, int out_size, void* d_ws, size_t ws_size,
                              hipStream_t stream) {
    const float* xyz = (const float*)d_in[0];
    const int*   z   = (const int*)  d_in[1];
    const float* emb = (const float*)d_in[2];
    const float* W1  = (const float*)d_in[3];
    const float* b1  = (const float*)d_in[4];
    const float* W2  = (const float*)d_in[5];
    const float* b2  = (const float*)d_in[6];
    const float* W3  = (const float*)d_in[7];
    const float* b3  = (const float*)d_in[8];
    float* out    = (float*)d_out;
    float* e_atom = (float*)d_ws;                       // [0, 6 KB)
    int*   flags  = (int*)((char*)d_ws + 8192);         // [8 KB, 14 KB)

    gnn_fused_kernel<<<N_ATOMS, 64, 0, stream>>>(
        xyz, z, emb, W1, b1, W2, b2, W3, b3, e_atom, flags, out);
}

// Round 9
// 32.036 us; speedup vs baseline: 1.0364x; 1.0364x over previous
//
#include <hip/hip_runtime.h>

#define N_ATOMS  1536
#define FEAT     32
#define N_GAUSS  16
#define MAXNBR   128
#define APB      16                   // atoms per block
#define NBLK     (N_ATOMS / APB)      // 96 blocks -> 96 serialized atomicAdds ~1.2us, mostly hidden
#define NTHREADS 512                  // 8 waves; wave w handles atoms w and w+8

// 2-node graph: memset(out,0,4B) -> fused kernel. One fp32 atomicAdd per block.
// R7/R8 lesson: in-kernel cross-WG sync (counter RMW / flag polling) costs more
// than a graph node; same-address RMWs ~13ns each -> keep count <= ~100.
__global__ __launch_bounds__(NTHREADS) void gnn_fused_kernel(
    const float* __restrict__ xyz, const int* __restrict__ z,
    const float* __restrict__ emb, const float* __restrict__ W1,
    const float* __restrict__ b1,  const float* __restrict__ W2,
    const float* __restrict__ b2,  const float* __restrict__ W3,
    const float* __restrict__ b3,  float* __restrict__ out)
{
    const int tid  = threadIdx.x;
    const int lane = tid & 63;
    const int w    = tid >> 6;            // wave 0..7
    const int a0   = blockIdx.x * APB;

    __shared__ float s_px[APB], s_py[APB], s_pz[APB];
    __shared__ int   s_nbr[APB][MAXNBR];
    __shared__ float s_dist[APB][MAXNBR];
    __shared__ int   s_cnt[APB];
    __shared__ float s_x[8][FEAT];        // per-wave scratch (same-wave write/read only)
    __shared__ float s_e[8];

    if (tid < APB) {
        s_cnt[tid] = 0;
        s_px[tid] = xyz[3*(a0+tid)+0];
        s_py[tid] = xyz[3*(a0+tid)+1];
        s_pz[tid] = xyz[3*(a0+tid)+2];
    }
    __syncthreads();

    // ---- Phase A: ONE shared scan (3 iters), 16 atoms per loaded position ----
    for (int j = tid; j < N_ATOMS; j += NTHREADS) {
        const float pjx = xyz[3*j+0], pjy = xyz[3*j+1], pjz = xyz[3*j+2];
        #pragma unroll
        for (int q = 0; q < APB; ++q) {
            float dx = pjx - s_px[q];
            float dy = pjy - s_py[q];
            float dz = pjz - s_pz[q];
            dx += (dx < -15.0f ? 30.0f : 0.0f) - (dx >= 15.0f ? 30.0f : 0.0f);
            dy += (dy < -15.0f ? 30.0f : 0.0f) - (dy >= 15.0f ? 30.0f : 0.0f);
            dz += (dz < -15.0f ? 30.0f : 0.0f) - (dz >= 15.0f ? 30.0f : 0.0f);
            float d2 = dx*dx + dy*dy + dz*dz;
            if (d2 < 25.0f && d2 > 0.0f) {
                int slot = atomicAdd(&s_cnt[q], 1);
                if (slot < MAXNBR) { s_nbr[q][slot] = j; s_dist[q][slot] = sqrtf(d2); }
            }
        }
    }
    __syncthreads();

    // ---- Phase B + MLP: wave-private, NO block barriers from here on ----
    const int fl   = lane & 7;
    const int slot = lane >> 3;
    const float4 b1v = *(const float4*)&b1[fl*4];
    float e_acc = 0.0f;

    #pragma unroll
    for (int r = 0; r < 2; ++r) {
        const int q  = w + 8*r;           // this wave's atom (0..15)
        const int ia = a0 + q;
        const int cnt = min(s_cnt[q], MAXNBR);
        float af[4] = {0.0f, 0.0f, 0.0f, 0.0f};

        for (int p = slot; p < cnt; p += 8) {
            const int   j  = s_nbr[q][p];
            const float d  = s_dist[q][p];
            const int   zj = z[j];
            float s0 = b1v.x, s1 = b1v.y, s2 = b1v.z, s3 = b1v.w;
            #pragma unroll
            for (int g = 0; g < N_GAUSS; ++g) {
                float t = d - (float)g * (5.0f / 15.0f);
                float rb = __expf(-10.0f * t * t);
                const float4 wv = *(const float4*)&W1[g * FEAT + fl * 4];
                s0 = fmaf(rb, wv.x, s0); s1 = fmaf(rb, wv.y, s1);
                s2 = fmaf(rb, wv.z, s2); s3 = fmaf(rb, wv.w, s3);
            }
            const float4 hj = *(const float4*)&emb[zj * FEAT + fl * 4];
            float sv[4] = {s0, s1, s2, s3};
            float hv[4] = {hj.x, hj.y, hj.z, hj.w};
            #pragma unroll
            for (int ff = 0; ff < 4; ++ff) {
                // tanh = (1-e)/(1+e), e=exp(-2s); |s|<~4 here so no overflow
                float ex = __expf(-2.0f * sv[ff]);
                float th = (1.0f - ex) / (1.0f + ex);
                af[ff] = fmaf(th, hv[ff], af[ff]);
            }
        }
        #pragma unroll
        for (int ff = 0; ff < 4; ++ff) {
            af[ff] += __shfl_xor(af[ff], 8,  64);
            af[ff] += __shfl_xor(af[ff], 16, 64);
            af[ff] += __shfl_xor(af[ff], 32, 64);
        }
        if (lane < 8) {
            const float4 hi = *(const float4*)&emb[z[ia] * FEAT + lane * 4];
            s_x[w][lane*4+0] = af[0] + hi.x;
            s_x[w][lane*4+1] = af[1] + hi.y;
            s_x[w][lane*4+2] = af[2] + hi.z;
            s_x[w][lane*4+3] = af[3] + hi.w;
        }
        // same-wave LDS write->read: program order + lgkmcnt suffices, no barrier

        float e = 0.0f;
        if (lane < FEAT) {
            float s = b2[lane];
            #pragma unroll
            for (int k = 0; k < FEAT; ++k)
                s = fmaf(s_x[w][k], W2[k * FEAT + lane], s);
            float u = s / (1.0f + __expf(-s));   // silu
            e = u * W3[lane];
        }
        e += __shfl_xor(e, 16, 64);
        e += __shfl_xor(e, 8,  64);
        e += __shfl_xor(e, 4,  64);
        e += __shfl_xor(e, 2,  64);
        e += __shfl_xor(e, 1,  64);
        e_acc += e;                       // full atom-energy now in every lane
    }

    if (lane == 0) s_e[w] = e_acc;
    __syncthreads();
    if (tid == 0) {
        float partial = s_e[0] + s_e[1] + s_e[2] + s_e[3]
                      + s_e[4] + s_e[5] + s_e[6] + s_e[7]
                      + (float)APB * b3[0];
        atomicAdd(out, partial);          // 96 total, ~hidden under stragglers
    }
}

extern "C" void kernel_launch(void* const* d_in, const int* in_sizes, int n_in,
                              void* d_out, int out_size, void* d_ws, size_t ws_size,
                              hipStream_t stream) {
    const float* xyz = (const float*)d_in[0];
    const int*   z   = (const int*)  d_in[1];
    const float* emb = (const float*)d_in[2];
    const float* W1  = (const float*)d_in[3];
    const float* b1  = (const float*)d_in[4];
    const float* W2  = (const float*)d_in[5];
    const float* b2  = (const float*)d_in[6];
    const float* W3  = (const float*)d_in[7];
    const float* b3  = (const float*)d_in[8];
    float* out = (float*)d_out;

    hipMemsetAsync(out, 0, sizeof(float), stream);
    gnn_fused_kernel<<<NBLK, NTHREADS, 0, stream>>>(
        xyz, z, emb, W1, b1, W2, b2, W3, b3, out);
}

// Round 10
// 18.654 us; speedup vs baseline: 1.7798x; 1.7174x over previous
//
#include <hip/hip_runtime.h>

#define N_ATOMS  1536
#define FEAT     32
#define N_GAUSS  16
#define MAXNBR   128   // ~30 expected neighbors; huge headroom
#define APB      2     // atoms per block, one per wave
#define NBLK     (N_ATOMS / APB)   // 768 blocks -> 3 blocks/CU, 6 waves/CU
#define NTHREADS 128               // 2 waves

// R6-champion structure, critical paths shaved:
//  - shared j-scan across 128 threads: 12 iters (was 24), APB=2 amortizes loads
//  - rint-based PBC wrap (3 VALU/axis vs 5; differs only at |comp|>=15 -> masked)
//  - 2 kernel nodes, no cross-WG sync (R7/R8/R9: all in-kernel schemes regressed)
__global__ __launch_bounds__(NTHREADS) void gnn_atom_kernel(
    const float* __restrict__ xyz, const int* __restrict__ z,
    const float* __restrict__ emb, const float* __restrict__ W1,
    const float* __restrict__ b1,  const float* __restrict__ W2,
    const float* __restrict__ b2,  const float* __restrict__ W3,
    float* __restrict__ e_atom)
{
    const int tid  = threadIdx.x;
    const int lane = tid & 63;
    const int w    = tid >> 6;          // wave 0..1
    const int a0   = blockIdx.x * APB;

    __shared__ float s_px[APB], s_py[APB], s_pz[APB];
    __shared__ int   s_nbr[APB][MAXNBR];
    __shared__ float s_dist[APB][MAXNBR];
    __shared__ float s_x[APB][FEAT];    // same-wave write/read only
    __shared__ int   s_cnt[APB];

    if (tid < APB) {
        s_cnt[tid] = 0;
        s_px[tid] = xyz[3*(a0+tid)+0];
        s_py[tid] = xyz[3*(a0+tid)+1];
        s_pz[tid] = xyz[3*(a0+tid)+2];
    }
    __syncthreads();

    // ---- Phase A: shared scan, 12 iters, each position tested vs both atoms ----
    const float inv_cell = 1.0f / 30.0f;
    for (int j = tid; j < N_ATOMS; j += NTHREADS) {
        const float pjx = xyz[3*j+0], pjy = xyz[3*j+1], pjz = xyz[3*j+2];
        #pragma unroll
        for (int q = 0; q < APB; ++q) {
            float dx = pjx - s_px[q];
            float dy = pjy - s_py[q];
            float dz = pjz - s_pz[q];
            dx = fmaf(-30.0f, rintf(dx * inv_cell), dx);
            dy = fmaf(-30.0f, rintf(dy * inv_cell), dy);
            dz = fmaf(-30.0f, rintf(dz * inv_cell), dz);
            float d2 = fmaf(dx, dx, fmaf(dy, dy, dz*dz));
            if (d2 < 25.0f && d2 > 0.0f) {
                int slot = atomicAdd(&s_cnt[q], 1);
                if (slot < MAXNBR) { s_nbr[q][slot] = j; s_dist[q][slot] = sqrtf(d2); }
            }
        }
    }
    __syncthreads();

    // ---- Phase B: wave w -> atom a0+w; 8 lanes/pair, 4 features/lane ----
    const int cnt  = min(s_cnt[w], MAXNBR);
    const int fl   = lane & 7;
    const int slot = lane >> 3;
    const float4 b1v = *(const float4*)&b1[fl*4];
    float af[4] = {0.0f, 0.0f, 0.0f, 0.0f};

    for (int p = slot; p < cnt; p += 8) {
        const int   j  = s_nbr[w][p];
        const float d  = s_dist[w][p];
        const int   zj = z[j];
        float s0 = b1v.x, s1 = b1v.y, s2 = b1v.z, s3 = b1v.w;
        #pragma unroll
        for (int g = 0; g < N_GAUSS; ++g) {
            float t = d - (float)g * (5.0f / 15.0f);
            float rb = __expf(-10.0f * t * t);
            const float4 wv = *(const float4*)&W1[g * FEAT + fl * 4];
            s0 = fmaf(rb, wv.x, s0); s1 = fmaf(rb, wv.y, s1);
            s2 = fmaf(rb, wv.z, s2); s3 = fmaf(rb, wv.w, s3);
        }
        const float4 hj = *(const float4*)&emb[zj * FEAT + fl * 4];
        float sv[4] = {s0, s1, s2, s3};
        float hv[4] = {hj.x, hj.y, hj.z, hj.w};
        #pragma unroll
        for (int ff = 0; ff < 4; ++ff) {
            float ex = __expf(-2.0f * sv[ff]);          // tanh = (1-e)/(1+e)
            float th = (1.0f - ex) / (1.0f + ex);
            af[ff] = fmaf(th, hv[ff], af[ff]);
        }
    }
    #pragma unroll
    for (int ff = 0; ff < 4; ++ff) {
        af[ff] += __shfl_xor(af[ff], 8,  64);
        af[ff] += __shfl_xor(af[ff], 16, 64);
        af[ff] += __shfl_xor(af[ff], 32, 64);
    }
    if (lane < 8) {
        const float4 hi = *(const float4*)&emb[z[a0 + w] * FEAT + lane * 4];
        s_x[w][lane*4+0] = af[0] + hi.x;
        s_x[w][lane*4+1] = af[1] + hi.y;
        s_x[w][lane*4+2] = af[2] + hi.z;
        s_x[w][lane*4+3] = af[3] + hi.w;
    }
    // same-wave LDS write->read: program order + lgkmcnt, no block barrier

    // ---- per-atom MLP on lanes 0..31 of wave w ----
    float e = 0.0f;
    if (lane < FEAT) {
        float s = b2[lane];
        #pragma unroll
        for (int k = 0; k < FEAT; ++k)
            s = fmaf(s_x[w][k], W2[k * FEAT + lane], s);
        float u = s / (1.0f + __expf(-s));   // silu
        e = u * W3[lane];
    }
    e += __shfl_xor(e, 16, 64);
    e += __shfl_xor(e, 8,  64);
    e += __shfl_xor(e, 4,  64);
    e += __shfl_xor(e, 2,  64);
    e += __shfl_xor(e, 1,  64);
    if (lane == 0) e_atom[a0 + w] = e;
}

// ---- kernel 2: one wave, float4 loads, 6-shuffle reduce ----
__global__ __launch_bounds__(64) void gnn_sum_kernel(
    const float* __restrict__ e_atom, const float* __restrict__ b3,
    float* __restrict__ out)
{
    const int tid = threadIdx.x;
    const float4* e4 = (const float4*)e_atom;
    float s = 0.0f;
    #pragma unroll
    for (int k = 0; k < N_ATOMS / (64 * 4); ++k) {      // 6 iters
        float4 v = e4[tid + k * 64];
        s += (v.x + v.y) + (v.z + v.w);
    }
    #pragma unroll
    for (int off = 32; off > 0; off >>= 1)
        s += __shfl_xor(s, off, 64);
    if (tid == 0) out[0] = s + (float)N_ATOMS * b3[0];
}

extern "C" void kernel_launch(void* const* d_in, const int* in_sizes, int n_in,
                              void* d_out, int out_size, void* d_ws, size_t ws_size,
                              hipStream_t stream) {
    const float* xyz = (const float*)d_in[0];
    const int*   z   = (const int*)  d_in[1];
    const float* emb = (const float*)d_in[2];
    const float* W1  = (const float*)d_in[3];
    const float* b1  = (const float*)d_in[4];
    const float* W2  = (const float*)d_in[5];
    const float* b2  = (const float*)d_in[6];
    const float* W3  = (const float*)d_in[7];
    const float* b3  = (const float*)d_in[8];
    float* out    = (float*)d_out;
    float* e_atom = (float*)d_ws;   // 1536 floats, float4-aligned

    gnn_atom_kernel<<<NBLK, NTHREADS, 0, stream>>>(xyz, z, emb, W1, b1, W2, b2, W3, e_atom);
    gnn_sum_kernel<<<1, 64, 0, stream>>>(e_atom, b3, out);
}

// Round 11
// 18.213 us; speedup vs baseline: 1.8229x; 1.0242x over previous
//
#include <hip/hip_runtime.h>

#define N_ATOMS  1536
#define FEAT     32
#define N_GAUSS  16
#define MAXNBR   128   // ~30 expected neighbors; huge headroom
#define APB      4     // atoms per block, one per wave
#define NBLK     (N_ATOMS / APB)   // 384 blocks -> ~1.5 blocks/CU, 6 waves/CU
#define NTHREADS 256               // 4 waves

// R10 champion + scan lever extrapolated: 6 scan iters (was 12), block-partial
// epilogue so k2 reads 384 floats (was 1536). 2 graph nodes, no cross-WG sync
// (R7/R8/R9: every in-kernel scheme regressed vs a second node).
__global__ __launch_bounds__(NTHREADS) void gnn_atom_kernel(
    const float* __restrict__ xyz, const int* __restrict__ z,
    const float* __restrict__ emb, const float* __restrict__ W1,
    const float* __restrict__ b1,  const float* __restrict__ W2,
    const float* __restrict__ b2,  const float* __restrict__ W3,
    float* __restrict__ p_blk)
{
    const int tid  = threadIdx.x;
    const int lane = tid & 63;
    const int w    = tid >> 6;          // wave 0..3
    const int a0   = blockIdx.x * APB;

    __shared__ float s_px[APB], s_py[APB], s_pz[APB];
    __shared__ int   s_nbr[APB][MAXNBR];
    __shared__ float s_dist[APB][MAXNBR];
    __shared__ float s_x[APB][FEAT];    // same-wave write/read only
    __shared__ int   s_cnt[APB];
    __shared__ float s_e[APB];

    if (tid < APB) {
        s_cnt[tid] = 0;
        s_px[tid] = xyz[3*(a0+tid)+0];
        s_py[tid] = xyz[3*(a0+tid)+1];
        s_pz[tid] = xyz[3*(a0+tid)+2];
    }
    __syncthreads();

    // ---- Phase A: shared scan, 6 iters, each position tested vs 4 atoms ----
    const float inv_cell = 1.0f / 30.0f;
    for (int j = tid; j < N_ATOMS; j += NTHREADS) {
        const float pjx = xyz[3*j+0], pjy = xyz[3*j+1], pjz = xyz[3*j+2];
        #pragma unroll
        for (int q = 0; q < APB; ++q) {
            float dx = pjx - s_px[q];
            float dy = pjy - s_py[q];
            float dz = pjz - s_pz[q];
            dx = fmaf(-30.0f, rintf(dx * inv_cell), dx);
            dy = fmaf(-30.0f, rintf(dy * inv_cell), dy);
            dz = fmaf(-30.0f, rintf(dz * inv_cell), dz);
            float d2 = fmaf(dx, dx, fmaf(dy, dy, dz*dz));
            if (d2 < 25.0f && d2 > 0.0f) {
                int slot = atomicAdd(&s_cnt[q], 1);
                if (slot < MAXNBR) { s_nbr[q][slot] = j; s_dist[q][slot] = sqrtf(d2); }
            }
        }
    }
    __syncthreads();

    // ---- Phase B: wave w -> atom a0+w; 8 lanes/pair, 4 features/lane ----
    const int cnt  = min(s_cnt[w], MAXNBR);
    const int fl   = lane & 7;
    const int slot = lane >> 3;
    const float4 b1v = *(const float4*)&b1[fl*4];
    float af[4] = {0.0f, 0.0f, 0.0f, 0.0f};

    for (int p = slot; p < cnt; p += 8) {
        const int   j  = s_nbr[w][p];
        const float d  = s_dist[w][p];
        const int   zj = z[j];
        float s0 = b1v.x, s1 = b1v.y, s2 = b1v.z, s3 = b1v.w;
        #pragma unroll
        for (int g = 0; g < N_GAUSS; ++g) {
            float t = d - (float)g * (5.0f / 15.0f);
            float rb = __expf(-10.0f * t * t);
            const float4 wv = *(const float4*)&W1[g * FEAT + fl * 4];
            s0 = fmaf(rb, wv.x, s0); s1 = fmaf(rb, wv.y, s1);
            s2 = fmaf(rb, wv.z, s2); s3 = fmaf(rb, wv.w, s3);
        }
        const float4 hj = *(const float4*)&emb[zj * FEAT + fl * 4];
        float sv[4] = {s0, s1, s2, s3};
        float hv[4] = {hj.x, hj.y, hj.z, hj.w};
        #pragma unroll
        for (int ff = 0; ff < 4; ++ff) {
            float ex = __expf(-2.0f * sv[ff]);          // tanh = (1-e)/(1+e)
            float th = (1.0f - ex) / (1.0f + ex);
            af[ff] = fmaf(th, hv[ff], af[ff]);
        }
    }
    #pragma unroll
    for (int ff = 0; ff < 4; ++ff) {
        af[ff] += __shfl_xor(af[ff], 8,  64);
        af[ff] += __shfl_xor(af[ff], 16, 64);
        af[ff] += __shfl_xor(af[ff], 32, 64);
    }
    if (lane < 8) {
        const float4 hi = *(const float4*)&emb[z[a0 + w] * FEAT + lane * 4];
        s_x[w][lane*4+0] = af[0] + hi.x;
        s_x[w][lane*4+1] = af[1] + hi.y;
        s_x[w][lane*4+2] = af[2] + hi.z;
        s_x[w][lane*4+3] = af[3] + hi.w;
    }
    // same-wave LDS write->read: program order + lgkmcnt, no block barrier

    // ---- per-atom MLP on lanes 0..31 of wave w ----
    float e = 0.0f;
    if (lane < FEAT) {
        float s = b2[lane];
        #pragma unroll
        for (int k = 0; k < FEAT; ++k)
            s = fmaf(s_x[w][k], W2[k * FEAT + lane], s);
        float u = s / (1.0f + __expf(-s));   // silu
        e = u * W3[lane];
    }
    e += __shfl_xor(e, 16, 64);
    e += __shfl_xor(e, 8,  64);
    e += __shfl_xor(e, 4,  64);
    e += __shfl_xor(e, 2,  64);
    e += __shfl_xor(e, 1,  64);

    // ---- block partial: one store per block ----
    if (lane == 0) s_e[w] = e;
    __syncthreads();
    if (tid == 0)
        p_blk[blockIdx.x] = (s_e[0] + s_e[1]) + (s_e[2] + s_e[3]);
}

// ---- kernel 2: one wave, 384 partials, 3 float2 loads/lane ----
__global__ __launch_bounds__(64) void gnn_sum_kernel(
    const float* __restrict__ p_blk, const float* __restrict__ b3,
    float* __restrict__ out)
{
    const int tid = threadIdx.x;
    const float2* p2 = (const float2*)p_blk;
    float s = 0.0f;
    #pragma unroll
    for (int k = 0; k < NBLK / (64 * 2); ++k) {   // 3 iters
        float2 v = p2[tid + k * 64];
        s += v.x + v.y;
    }
    #pragma unroll
    for (int off = 32; off > 0; off >>= 1)
        s += __shfl_xor(s, off, 64);
    if (tid == 0) out[0] = s + (float)N_ATOMS * b3[0];
}

extern "C" void kernel_launch(void* const* d_in, const int* in_sizes, int n_in,
                              void* d_out, int out_size, void* d_ws, size_t ws_size,
                              hipStream_t stream) {
    const float* xyz = (const float*)d_in[0];
    const int*   z   = (const int*)  d_in[1];
    const float* emb = (const float*)d_in[2];
    const float* W1  = (const float*)d_in[3];
    const float* b1  = (const float*)d_in[4];
    const float* W2  = (const float*)d_in[5];
    const float* b2  = (const float*)d_in[6];
    const float* W3  = (const float*)d_in[7];
    const float* b3  = (const float*)d_in[8];
    float* out   = (float*)d_out;
    float* p_blk = (float*)d_ws;   // 384 floats, float2-aligned

    gnn_atom_kernel<<<NBLK, NTHREADS, 0, stream>>>(xyz, z, emb, W1, b1, W2, b2, W3, p_blk);
    gnn_sum_kernel<<<1, 64, 0, stream>>>(p_blk, b3, out);
}